// Round 9
// baseline (236.329 us; speedup 1.0000x reference)
//
#include <hip/hip_runtime.h>
#include <cstdint>
#include <cstddef>

typedef unsigned short u16;
typedef short short8 __attribute__((ext_vector_type(8)));
typedef float floatx4 __attribute__((ext_vector_type(4)));

#define DEVINL __device__ __forceinline__

static constexpr int BSZ = 8, SEQL = 4096, H = 512, P = 256;
static constexpr int M = BSZ * SEQL;       // 32768 rows
static constexpr int KD = 512;             // K for both GEMMs
static constexpr int ND = 512;             // N for both GEMMs
static constexpr int CHUNK = 64;           // = gemm0 wave row-half -> carry from acc regs
static constexpr int NCH = SEQL / CHUNK;   // 64 chunks

DEVINL u16 f2bf(float f) {
  union { float f; unsigned u; } v; v.f = f;
  unsigned r = (v.u + 0x7fffu + ((v.u >> 16) & 1u)) >> 16;
  return (u16)r;
}
DEVINL float bf2f(u16 h) {
  union { unsigned u; float f; } v; v.u = ((unsigned)h) << 16; return v.f;
}
DEVINL float2 cmul(float2 a, float2 b) {
  return make_float2(a.x * b.x - a.y * b.y, a.x * b.y + a.y * b.x);
}

// async global->LDS, 16B per lane. LDS dest must be wave-uniform base + lane*16.
DEVINL void gload_lds16(const void* g, void* l) {
  __builtin_amdgcn_global_load_lds(
      (const __attribute__((address_space(1))) unsigned*)g,
      (__attribute__((address_space(3))) unsigned*)l, 16, 0, 0);
}

// ---------- prep: bt1, bt2, and lambda power tables (lam, lam^4, lam^13) ----------
__global__ void prep_kernel(const float2* __restrict__ Bin, const float* __restrict__ Cin,
                            const float* __restrict__ Lre, const float* __restrict__ Lim,
                            const float* __restrict__ lstep,
                            u16* __restrict__ bt1, u16* __restrict__ bt2,
                            float2* __restrict__ lamt, float2* __restrict__ lam4t,
                            float2* __restrict__ lam13t) {
  int bid = blockIdx.x;
  if (bid < 512) {
    int idx = bid * 256 + threadIdx.x;   // over P*H
    int p = idx / H, h = idx % H;
    float lr = Lre[p], li = Lim[p];
    float st = expf(lstep[p]);
    float mag = expf(lr * st);
    float ang = li * st;
    float cr = mag * cosf(ang), ci = mag * sinf(ang);
    float a = cr - 1.0f, b = ci;
    float den = lr * lr + li * li;
    float fr = (a * lr + b * li) / den;
    float fi = (b * lr - a * li) / den;
    float2 bv = Bin[(size_t)p * H + h];
    float br = fr * bv.x - fi * bv.y;
    float bi = fr * bv.y + fi * bv.x;
    bt1[(size_t)(2 * p) * H + h]     = f2bf(br);
    bt1[(size_t)(2 * p + 1) * H + h] = f2bf(bi);
  } else if (bid < 1536) {
    int idx = (bid - 512) * 256 + threadIdx.x;   // over H*P*2
    float c = Cin[idx];
    float v = (idx & 1) ? -2.0f * c : 2.0f * c;
    bt2[idx] = f2bf(v);
  } else {
    int p = threadIdx.x;   // 256 threads
    float lr = Lre[p], li = Lim[p];
    float st = expf(lstep[p]);
    float mag = expf(lr * st);
    float ang = li * st;
    float2 lm = make_float2(mag * cosf(ang), mag * sinf(ang));
    float2 l2 = cmul(lm, lm);
    float2 l4 = cmul(l2, l2);
    float2 l8 = cmul(l4, l4);
    float2 l13 = cmul(cmul(l8, l4), lm);
    lamt[p] = lm; lam4t[p] = l4; lam13t[p] = l13;
  }
}

// ---------- u (f32) -> u_bf (bf16), 4 per thread (R1-proven) ----------
__global__ void ucvt_kernel(const float4* __restrict__ uin, ushort4* __restrict__ ubf) {
  int idx = blockIdx.x * 256 + threadIdx.x;   // over M*H/4
  float4 f = uin[idx];
  ushort4 o;
  o.x = f2bf(f.x); o.y = f2bf(f.y); o.z = f2bf(f.z); o.w = f2bf(f.w);
  ubf[idx] = o;
}

// ---------- GEMM0: Bu[M][N] = ubf[M][K] * bt1[N][K]^T, + in-register carry ----------
// Main loop = R1's measured-best 2-stage dbuf. Carry epilogue: each wave owns a
// 64-row x 64-col C-quadrant in acc; carry(chunk) = sum_l lam^(63-l)*C[l][n] is
// computed per lane by an ascending-row chain (mult lam, lam^13 at tm gaps),
// scaled by (lam^4)^(3-quad), quad-butterfly (shfl 16/32), even/odd column pair
// (shfl 1) -> complex carry. No global re-read, no barrier (register-only).
__global__ __launch_bounds__(256, 4) void gemm0(const u16* __restrict__ A,
                                                const u16* __restrict__ Bt,
                                                u16* __restrict__ outBf,
                                                const float2* __restrict__ lamt,
                                                const float2* __restrict__ lam4t,
                                                const float2* __restrict__ lam13t,
                                                float2* __restrict__ carry) {
  __shared__ u16 As[2][128 * 32];   // 2 x 8 KB
  __shared__ u16 Bs[2][128 * 32];   // 2 x 8 KB
  const int tid = threadIdx.x;
  const int bm = blockIdx.x, bn = blockIdx.y;
  const int wave = tid >> 6, lane = tid & 63;
  const int quad = lane >> 4, l16 = lane & 15;
  const int wm = (wave & 1) << 6, wn = (wave >> 1) << 6;

  floatx4 acc[4][4] = {};

  const u16* Ab = A + (size_t)bm * 128 * KD;
  const u16* Bb = Bt + (size_t)bn * 128 * KD;
  const int srow = tid >> 2;
  const int scol = (tid & 3) << 3;

#define STAGE0(buf, kofs)                                                                  \
  do {                                                                                     \
    gload_lds16(Ab + (size_t)srow * KD + (kofs) + scol,        &As[buf][tid * 8]);         \
    gload_lds16(Ab + (size_t)(srow + 64) * KD + (kofs) + scol, &As[buf][2048 + tid * 8]);  \
    gload_lds16(Bb + (size_t)srow * KD + (kofs) + scol,        &Bs[buf][tid * 8]);         \
    gload_lds16(Bb + (size_t)(srow + 64) * KD + (kofs) + scol, &Bs[buf][2048 + tid * 8]);  \
  } while (0)

  STAGE0(0, 0);
  asm volatile("s_waitcnt vmcnt(0)" ::: "memory");
  __builtin_amdgcn_sched_barrier(0);
  __builtin_amdgcn_s_barrier();

  int cur = 0;
  for (int k0 = 0; k0 < KD; k0 += 32) {
    if (k0 + 32 < KD) STAGE0(cur ^ 1, k0 + 32);

    short8 af[4], bfr[4];
#pragma unroll
    for (int t = 0; t < 4; t++)
      af[t] = *(const short8*)&As[cur][(wm + t * 16 + l16) * 32 + quad * 8];
#pragma unroll
    for (int t = 0; t < 4; t++)
      bfr[t] = *(const short8*)&Bs[cur][(wn + t * 16 + l16) * 32 + quad * 8];

    asm volatile("s_waitcnt lgkmcnt(0)" ::: "memory");
    __builtin_amdgcn_sched_barrier(0);

    __builtin_amdgcn_s_setprio(1);
#pragma unroll
    for (int tm = 0; tm < 4; tm++)
#pragma unroll
      for (int tn = 0; tn < 4; tn++)
        acc[tm][tn] = __builtin_amdgcn_mfma_f32_16x16x32_bf16(af[tm], bfr[tn], acc[tm][tn], 0, 0, 0);
    __builtin_amdgcn_s_setprio(0);

    asm volatile("s_waitcnt vmcnt(0)" ::: "memory");
    __builtin_amdgcn_sched_barrier(0);
    __builtin_amdgcn_s_barrier();
    cur ^= 1;
  }
#undef STAGE0

  // epilogue: C/D layout col = lane&15, row = quad*4 + reg  [m89-verified]
  const int row_base = bm * 128 + wm + quad * 4;
  const int col_base = bn * 128 + wn + l16;
#pragma unroll
  for (int tm = 0; tm < 4; tm++)
#pragma unroll
    for (int tn = 0; tn < 4; tn++) {
      int n = col_base + tn * 16;
#pragma unroll
      for (int r = 0; r < 4; r++) {
        int m = row_base + tm * 16 + r;
        outBf[(size_t)m * ND + n] = f2bf(acc[tm][tn][r]);
      }
    }

  // ---- in-register carry (per wave = one 64-row half-chunk) ----
  // Lane's local rows: l = quad*4 + tm*16 + r (l in [0,64)). Ascending chain:
  // s = s*mult + c with mult = lam^13 at tm-gap (r==0), lam otherwise ->
  // s = sum lam^(lmax-l) c_l, lmax = quad*4+51. Scale lam^(63-lmax) = (lam^4)^(3-quad).
  {
    const int half = wave & 1;                 // wm = half*64
    const int cix = ((bm & 31) << 1) | half;   // chunk index within batch
    const int b = bm >> 5;
#pragma unroll
    for (int tn = 0; tn < 4; tn++) {
      const int n = col_base + tn * 16;
      const int p = n >> 1;                    // same for the even/odd lane pair
      const float2 lm = lamt[p];
      const float2 l4 = lam4t[p];
      const float2 l13 = lam13t[p];
      float2 s = make_float2(0.f, 0.f);
#pragma unroll
      for (int tm = 0; tm < 4; tm++)
#pragma unroll
        for (int r = 0; r < 4; r++) {
          float2 mult = (r == 0) ? l13 : lm;   // (tm==0,r==0): s==0, mult irrelevant
          s = cmul(s, mult);
          s.x += acc[tm][tn][r];
        }
#pragma unroll
      for (int i = 0; i < 3; i++)
        if (i < 3 - quad) s = cmul(s, l4);
      // sum across the 4 quads holding this column
      s.x += __shfl_xor(s.x, 16); s.y += __shfl_xor(s.y, 16);
      s.x += __shfl_xor(s.x, 32); s.y += __shfl_xor(s.y, 32);
      // pair even/odd columns: carry = S(2p) + i*S(2p+1)
      float oR = __shfl_xor(s.x, 1), oI = __shfl_xor(s.y, 1);
      if (!(lane & 1)) {
        carry[((size_t)b * NCH + cix) * P + p] = make_float2(s.x - oI, s.y + oR);
      }
    }
  }
}

// ---------- GEMM1: ys = xs[M][K] * bt2[N][K]^T + D[n]*u_bf, gelu -> f32 ----------
// R1's measured-best structure, unchanged (epilogue reads bf16 ubf).
__global__ __launch_bounds__(256, 4) void gemm1(const u16* __restrict__ A,
                                                const u16* __restrict__ Bt,
                                                float* __restrict__ outF,
                                                const float* __restrict__ Dv,
                                                const u16* __restrict__ ubf) {
  __shared__ u16 As[2][128 * 32];   // 2 x 8 KB
  __shared__ u16 Bs[2][128 * 32];   // 2 x 8 KB
  const int tid = threadIdx.x;
  const int bm = blockIdx.x, bn = blockIdx.y;
  const int wave = tid >> 6, lane = tid & 63;
  const int quad = lane >> 4, l16 = lane & 15;
  const int wm = (wave & 1) << 6, wn = (wave >> 1) << 6;

  floatx4 acc[4][4] = {};

  const u16* Ab = A + (size_t)bm * 128 * KD;
  const u16* Bb = Bt + (size_t)bn * 128 * KD;
  const int srow = tid >> 2;
  const int scol = (tid & 3) << 3;

#define STAGE1(buf, kofs)                                                                  \
  do {                                                                                     \
    gload_lds16(Ab + (size_t)srow * KD + (kofs) + scol,        &As[buf][tid * 8]);         \
    gload_lds16(Ab + (size_t)(srow + 64) * KD + (kofs) + scol, &As[buf][2048 + tid * 8]);  \
    gload_lds16(Bb + (size_t)srow * KD + (kofs) + scol,        &Bs[buf][tid * 8]);         \
    gload_lds16(Bb + (size_t)(srow + 64) * KD + (kofs) + scol, &Bs[buf][2048 + tid * 8]);  \
  } while (0)

  STAGE1(0, 0);
  asm volatile("s_waitcnt vmcnt(0)" ::: "memory");
  __builtin_amdgcn_sched_barrier(0);
  __builtin_amdgcn_s_barrier();

  int cur = 0;
  for (int k0 = 0; k0 < KD; k0 += 32) {
    if (k0 + 32 < KD) STAGE1(cur ^ 1, k0 + 32);

    short8 af[4], bfr[4];
#pragma unroll
    for (int t = 0; t < 4; t++)
      af[t] = *(const short8*)&As[cur][(wm + t * 16 + l16) * 32 + quad * 8];
#pragma unroll
    for (int t = 0; t < 4; t++)
      bfr[t] = *(const short8*)&Bs[cur][(wn + t * 16 + l16) * 32 + quad * 8];

    asm volatile("s_waitcnt lgkmcnt(0)" ::: "memory");
    __builtin_amdgcn_sched_barrier(0);

    __builtin_amdgcn_s_setprio(1);
#pragma unroll
    for (int tm = 0; tm < 4; tm++)
#pragma unroll
      for (int tn = 0; tn < 4; tn++)
        acc[tm][tn] = __builtin_amdgcn_mfma_f32_16x16x32_bf16(af[tm], bfr[tn], acc[tm][tn], 0, 0, 0);
    __builtin_amdgcn_s_setprio(0);

    asm volatile("s_waitcnt vmcnt(0)" ::: "memory");
    __builtin_amdgcn_sched_barrier(0);
    __builtin_amdgcn_s_barrier();
    cur ^= 1;
  }
#undef STAGE1

  const int row_base = bm * 128 + wm + quad * 4;
  const int col_base = bn * 128 + wn + l16;
  float dv[4];
#pragma unroll
  for (int tn = 0; tn < 4; tn++) dv[tn] = Dv[col_base + tn * 16];
#pragma unroll
  for (int tm = 0; tm < 4; tm++)
#pragma unroll
    for (int tn = 0; tn < 4; tn++) {
      int n = col_base + tn * 16;
#pragma unroll
      for (int r = 0; r < 4; r++) {
        int m = row_base + tm * 16 + r;
        float uv = bf2f(ubf[(size_t)m * ND + n]);
        float ys = acc[tm][tn][r] + dv[tn] * uv;
        // gelu(ys) = ys * sigmoid(1.59577*(ys + 0.044715*ys^3)); exp via HW exp2
        float zz = ys + 0.044715f * (ys * ys * ys);
        float e = __builtin_amdgcn_exp2f(-2.3022082f * zz);
        outF[(size_t)m * ND + n] = ys * __builtin_amdgcn_rcpf(1.0f + e);
      }
    }
}

// ---------- scan apply: batched prefix over <=63 carries, then 64-row apply ----------
__global__ __launch_bounds__(256) void scan_apply(u16* __restrict__ Bu,
                                                  const float2* __restrict__ lamt,
                                                  const float2* __restrict__ carry) {
  int p = threadIdx.x;
  int c = blockIdx.x;       // 0..63
  int b = blockIdx.y;
  float2 lm = lamt[p];
  // A = lm^CHUNK (CHUNK = 64 = 2^6)
  float ar = lm.x, ai = lm.y;
#pragma unroll
  for (int i = 0; i < 6; i++) { float nr = ar * ar - ai * ai, ni = 2.f * ar * ai; ar = nr; ai = ni; }
  // prefix_c: q <- A*q + carry_j over j in [0,c), 16-deep batched loads (R6-proven)
  float pr = 0.f, pi = 0.f;
  const float2* cb_base = carry + (size_t)b * NCH * P + p;
  for (int j0 = 0; j0 < c; j0 += 16) {
    float2 cb[16];
#pragma unroll
    for (int t = 0; t < 16; t++) {
      int j = j0 + t;
      int jc = j < c ? j : c - 1;          // clamp address (loop entered => c >= 1)
      cb[t] = cb_base[(size_t)jc * P];
    }
#pragma unroll
    for (int t = 0; t < 16; t++) {
      bool real = (j0 + t) < c;
      float mr = real ? ar : 1.0f;
      float mi = real ? ai : 0.0f;
      float cx = real ? cb[t].x : 0.0f;
      float cy = real ? cb[t].y : 0.0f;
      float nr = mr * pr - mi * pi + cx;
      float ni = mr * pi + mi * pr + cy;
      pr = nr; pi = ni;
    }
  }
  // apply over the 64-row chunk, 8-deep load batches (R8-proven), write xs in place
  float xr = pr, xi = pi;
  u16* base = Bu + ((size_t)b * SEQL + (size_t)c * CHUNK) * 512 + 2 * p;
  for (int l0 = 0; l0 < CHUNK; l0 += 8) {
    unsigned w[8];
#pragma unroll
    for (int t = 0; t < 8; t++)
      w[t] = *(const unsigned*)(base + (size_t)(l0 + t) * 512);
#pragma unroll
    for (int t = 0; t < 8; t++) {
      float br = bf2f((u16)(w[t] & 0xffffu));
      float bi = bf2f((u16)(w[t] >> 16));
      float nr = lm.x * xr - lm.y * xi + br;
      float ni = lm.x * xi + lm.y * xr + bi;
      xr = nr; xi = ni;
      *(unsigned*)(base + (size_t)(l0 + t) * 512) = (unsigned)f2bf(nr) | ((unsigned)f2bf(ni) << 16);
    }
  }
}

extern "C" void kernel_launch(void* const* d_in, const int* in_sizes, int n_in,
                              void* d_out, int out_size, void* d_ws, size_t ws_size,
                              hipStream_t stream) {
  const float* u      = (const float*)d_in[0];   // (8,4096,512)
  const float* Lre    = (const float*)d_in[1];   // (256,)
  const float* Lim    = (const float*)d_in[2];   // (256,)
  const float* Bin    = (const float*)d_in[3];   // (256,512,2)
  const float* Cin    = (const float*)d_in[4];   // (512,256,2)
  const float* Dv     = (const float*)d_in[5];   // (512,)
  const float* lstep  = (const float*)d_in[6];   // (256,1)
  float* out          = (float*)d_out;           // (8,4096,512) f32

  char* ws = (char*)d_ws;
  u16*    bt1    = (u16*)   (ws + 0);                 // 512 KB
  u16*    bt2    = (u16*)   (ws + 524288);            // 512 KB
  float2* lamt   = (float2*)(ws + 1048576);           //   2 KB
  float2* lam4t  = (float2*)(ws + 1050624);           //   2 KB
  float2* lam13t = (float2*)(ws + 1052672);           //   2 KB
  u16*    ubf    = (u16*)   (ws + 1054720);           //  32 MB
  u16*    Bu     = (u16*)   (ws + 34609152);          //  32 MB (becomes xs)
  float2* carry  = (float2*)(ws + 68163584);          //   1 MB

  prep_kernel<<<1537, 256, 0, stream>>>((const float2*)Bin, Cin, Lre, Lim, lstep,
                                        bt1, bt2, lamt, lam4t, lam13t);
  ucvt_kernel<<<(M * H / 4) / 256, 256, 0, stream>>>((const float4*)u, (ushort4*)ubf);

  gemm0<<<dim3(M / 128, ND / 128), 256, 0, stream>>>(ubf, bt1, Bu, lamt, lam4t, lam13t, carry);

  scan_apply<<<dim3(NCH, BSZ), 256, 0, stream>>>(Bu, lamt, carry);

  gemm1<<<dim3(M / 128, ND / 128), 256, 0, stream>>>(Bu, bt2, out, Dv, ubf);
}